// Round 1
// baseline (27761.136 us; speedup 1.0000x reference)
//
#include <hip/hip_runtime.h>
#include <math.h>

// Problem constants
#define Vv 32000
#define Ee 512
#define Hh 1024
#define H3 3072
#define Ss 64
#define Tt 64
#define Bb 32
#define DEC_T 63     // T-1 teacher-forced steps
#define KS 16        // k-slices for recurrent GEMV partials
#define KSL 64       // slice length (KS*KSL = 1024)
#define PAD_TOK 1
#define NEGV -100000.0f
#define PGRID 256u   // persistent grid: 256 blocks (<= 1/CU even at worst occupancy)

__device__ __forceinline__ float sigmoidf_(float x) {
  return 1.0f / (1.0f + __expf(-x));
}

// ---------------- transpose: src[R][C] -> dst[C][R] ----------------
__global__ __launch_bounds__(256) void transpose_k(const float* __restrict__ src,
                                                   float* __restrict__ dst,
                                                   int R, int C) {
  __shared__ float tile[32][33];
  int r0 = blockIdx.y * 32, c0 = blockIdx.x * 32;
  int tx = threadIdx.x & 31, ty = threadIdx.x >> 5;
  for (int i = ty; i < 32; i += 8)
    tile[i][tx] = src[(long)(r0 + i) * C + c0 + tx];
  __syncthreads();
  for (int i = ty; i < 32; i += 8)
    dst[(long)(c0 + i) * R + r0 + tx] = tile[tx][i];
}

// ---------------- generic fp32 GEMM: C[m][n] = sum_k A[m][k]*W[n][k] + bias[n]
// A rows optionally gathered via idx (embedding lookup). N must be mult of 128.
template <int ACT>
__global__ __launch_bounds__(256) void gemm_nt(
    const float* __restrict__ A, const int* __restrict__ idx, int lda,
    const float* __restrict__ W, int ldw,
    const float* __restrict__ bias,
    float* __restrict__ C, long ldc,
    int M, int N, int K) {
  __shared__ float As[8][132];
  __shared__ float Ws[8][132];
  int tid = threadIdx.x;
  int n0 = blockIdx.x * 128;
  int m0 = blockIdx.y * 128;
  int sr = tid >> 1;          // 0..127 staged row
  int sk = (tid & 1) * 4;     // 0 or 4
  int am = m0 + sr;
  bool aval = am < M;
  int amc = aval ? am : (M - 1);
  const float* arow = A + (idx ? (long)idx[amc] * lda : (long)amc * lda);
  const float* wrow = W + (long)(n0 + sr) * ldw;
  int tx = tid & 15, ty = tid >> 4;
  float acc[8][8];
#pragma unroll
  for (int i = 0; i < 8; i++)
#pragma unroll
    for (int j = 0; j < 8; j++) acc[i][j] = 0.f;

  for (int k0 = 0; k0 < K; k0 += 8) {
    float4 av = aval ? *(const float4*)(arow + k0 + sk) : make_float4(0.f, 0.f, 0.f, 0.f);
    float4 wv = *(const float4*)(wrow + k0 + sk);
    __syncthreads();
    As[sk + 0][sr] = av.x; As[sk + 1][sr] = av.y; As[sk + 2][sr] = av.z; As[sk + 3][sr] = av.w;
    Ws[sk + 0][sr] = wv.x; Ws[sk + 1][sr] = wv.y; Ws[sk + 2][sr] = wv.z; Ws[sk + 3][sr] = wv.w;
    __syncthreads();
#pragma unroll
    for (int k = 0; k < 8; k++) {
      float a[8], w[8];
      *(float4*)(a) = *(const float4*)&As[k][ty * 8];
      *(float4*)(a + 4) = *(const float4*)&As[k][ty * 8 + 4];
      *(float4*)(w) = *(const float4*)&Ws[k][tx * 8];
      *(float4*)(w + 4) = *(const float4*)&Ws[k][tx * 8 + 4];
#pragma unroll
      for (int i = 0; i < 8; i++)
#pragma unroll
        for (int j = 0; j < 8; j++) acc[i][j] = fmaf(a[i], w[j], acc[i][j]);
    }
  }
#pragma unroll
  for (int i = 0; i < 8; i++) {
    int m = m0 + ty * 8 + i;
    if (m < M) {
      float* crow = C + (long)m * ldc + n0 + tx * 8;
#pragma unroll
      for (int j = 0; j < 8; j++) {
        float v = acc[i][j] + bias[n0 + tx * 8 + j];
        if (ACT == 1) v = tanhf(v);
        crow[j] = v;
      }
    }
  }
}

// ---------------- device-scope grid barrier (monotone epoch, no reset) ------
// bar[0]   : arrival counter (atomicAdd, agent scope)
// bar[32]  : release flag (separate cacheline; spinners poll loads only)
__device__ __forceinline__ void gbar(unsigned* bar, unsigned& ep) {
  __syncthreads();
  if (threadIdx.x == 0) {
    ep += 1u;
    unsigned old = __hip_atomic_fetch_add(bar, 1u, __ATOMIC_ACQ_REL,
                                          __HIP_MEMORY_SCOPE_AGENT);
    if (old == ep * PGRID - 1u) {
      // last arriver: publish epoch
      __hip_atomic_store(bar + 32, ep, __ATOMIC_RELEASE, __HIP_MEMORY_SCOPE_AGENT);
    } else {
      while (__hip_atomic_load(bar + 32, __ATOMIC_ACQUIRE,
                               __HIP_MEMORY_SCOPE_AGENT) < ep)
        __builtin_amdgcn_s_sleep(3);
    }
  }
  __syncthreads();
}

// ---------------- one GEMV partial job (identical math to old rec_gemv) -----
// part[ks][b][j..j+3] = sum_{k in slice ks} x[b][k] * Wt[k][j..j+3]
__device__ __forceinline__ void gemv_job(
    const float* __restrict__ x, const float* __restrict__ Wt,
    float* __restrict__ part, int jt, int ks, int tid, float* xs /*[32][68]*/) {
  __syncthreads();  // protect xs reuse across consecutive jobs / phases
  {
    int r = tid >> 3;
    int c = (tid & 7) * 8;
    const float* xp = x + r * Hh + ks * KSL + c;
    float4 v0 = *(const float4*)(xp);
    float4 v1 = *(const float4*)(xp + 4);
    *(float4*)&xs[r * 68 + c] = v0;
    *(float4*)&xs[r * 68 + c + 4] = v1;
  }
  __syncthreads();
  int txj = tid & 63;   // all lanes of a wave share bg => x broadcast
  int bg = tid >> 6;    // 0..3 -> 8 batches each
  int j = jt * 256 + txj * 4;
  float acc[8][4];
#pragma unroll
  for (int bb = 0; bb < 8; bb++)
#pragma unroll
    for (int q = 0; q < 4; q++) acc[bb][q] = 0.f;
  const float* wp = Wt + (size_t)(ks * KSL) * H3 + j;
#pragma unroll 4
  for (int k = 0; k < KSL; k++) {
    float4 w = *(const float4*)(wp);
    wp += H3;
#pragma unroll
    for (int bb = 0; bb < 8; bb++) {
      float xv = xs[(bg * 8 + bb) * 68 + k];
      acc[bb][0] = fmaf(xv, w.x, acc[bb][0]);
      acc[bb][1] = fmaf(xv, w.y, acc[bb][1]);
      acc[bb][2] = fmaf(xv, w.z, acc[bb][2]);
      acc[bb][3] = fmaf(xv, w.w, acc[bb][3]);
    }
  }
#pragma unroll
  for (int bb = 0; bb < 8; bb++) {
    int b = bg * 8 + bb;
    float4 v;
    v.x = acc[bb][0]; v.y = acc[bb][1]; v.z = acc[bb][2]; v.w = acc[bb][3];
    *(float4*)&part[((size_t)ks * Bb + b) * H3 + j] = v;
  }
}

// ---------------- persistent recurrence: all steps of one stack in 1 launch.
// Per step: A) pgh0 = h0@Whh0t, pgh1 = h1@Whh1t (384 jobs)
//           B) h0 <- GRU(gx[s], sum pgh0)            (128 job-blocks)
//           C) pgx1 = h0@Wih1t                       (192 jobs)
//           D) h1 <- GRU(sum pgx1, sum pgh1), out2   (128 job-blocks)
// 4 grid barriers/step. Grid MUST be PGRID blocks.
__global__ __launch_bounds__(256, 2) void recurrence_pers(
    const float* __restrict__ gx,      // [nsteps][32][3072] input gates (x-side L0)
    const float* __restrict__ Whh0t, const float* __restrict__ Wih1t,
    const float* __restrict__ Whh1t,
    const float* __restrict__ bhh0,
    const float* __restrict__ bih1, const float* __restrict__ bhh1,
    float* __restrict__ h0, float* __restrict__ h1,
    float* __restrict__ pgh0, float* __restrict__ pgx1, float* __restrict__ pgh1,
    float* __restrict__ out2, long os, int nsteps, unsigned* bar) {
  __shared__ float xs[32 * 68];
  int bid = blockIdx.x;
  int tid = threadIdx.x;
  unsigned ep = 0;
  for (int s = 0; s < nsteps; s++) {
    // ---- phase A: recurrent partials for both h-GEMVs ----
    for (int vj = bid; vj < 384; vj += (int)PGRID) {
      int m = vj / 192, r = vj % 192;
      int jt = r % 12, ks = r / 12;
      if (m == 0) gemv_job(h0, Whh0t, pgh0, jt, ks, tid, xs);
      else        gemv_job(h1, Whh1t, pgh1, jt, ks, tid, xs);
    }
    gbar(bar, ep);
    // ---- phase B: layer0 GRU update (in place) ----
    if (bid < 128) {
      int t = bid * 256 + tid;
      int b = t >> 10, i = t & 1023;
      float hr = bhh0[i], hz = bhh0[Hh + i], hn = bhh0[2 * Hh + i];
#pragma unroll 4
      for (int ks = 0; ks < KS; ks++) {
        const float* p = pgh0 + ((size_t)ks * Bb + b) * H3 + i;
        hr += p[0]; hz += p[Hh]; hn += p[2 * Hh];
      }
      const float* g = gx + (size_t)s * Bb * H3 + (size_t)b * H3 + i;
      float r = sigmoidf_(g[0] + hr);
      float z = sigmoidf_(g[Hh] + hz);
      float n = tanhf(g[2 * Hh] + r * hn);
      h0[t] = (1.f - z) * n + z * h0[t];
    }
    gbar(bar, ep);
    // ---- phase C: layer1 x-side partials ----
    if (bid < 192) {
      int jt = bid % 12, ks = bid / 12;
      gemv_job(h0, Wih1t, pgx1, jt, ks, tid, xs);
    }
    gbar(bar, ep);
    // ---- phase D: layer1 GRU update + secondary store ----
    if (bid < 128) {
      int t = bid * 256 + tid;
      int b = t >> 10, i = t & 1023;
      float xr = bih1[i], xz = bih1[Hh + i], xn = bih1[2 * Hh + i];
      float hr = bhh1[i], hz = bhh1[Hh + i], hn = bhh1[2 * Hh + i];
#pragma unroll 4
      for (int ks = 0; ks < KS; ks++) {
        const float* px = pgx1 + ((size_t)ks * Bb + b) * H3 + i;
        const float* ph = pgh1 + ((size_t)ks * Bb + b) * H3 + i;
        xr += px[0]; xz += px[Hh]; xn += px[2 * Hh];
        hr += ph[0]; hz += ph[Hh]; hn += ph[2 * Hh];
      }
      float r = sigmoidf_(xr + hr);
      float z = sigmoidf_(xz + hz);
      float n = tanhf(xn + r * hn);
      float hv = (1.f - z) * n + z * h1[t];
      h1[t] = hv;
      out2[((size_t)s * Bb + b) * os + i] = hv;
    }
    gbar(bar, ep);
  }
}

// ---------------- batched attention scores + masked softmax. one block per (t,b).
__global__ __launch_bounds__(256) void attn_kernel(
    const float* __restrict__ h1cat,   // [2016][2048], first half = h1
    const float* __restrict__ enc_out, // [64][32][1024]
    const int* __restrict__ src_tok,   // [64][32]
    float* __restrict__ attn) {        // [2016][64]
  int tb = blockIdx.x;
  int b = tb & 31;
  __shared__ float hs[1024];
  __shared__ float sc[64][4];
  __shared__ float red[64];
  int tid = threadIdx.x;
  const float* h1 = h1cat + (long)tb * 2048;
  for (int i = tid; i < 1024; i += 256) hs[i] = h1[i];
  __syncthreads();
  int s = tid >> 2, q = tid & 3;
  const float* eo = enc_out + ((long)s * Bb + b) * Hh + q * 256;
  float p = 0.f;
  for (int k = 0; k < 256; k += 4) {
    float4 e = *(const float4*)(eo + k);
    const float* hq = hs + q * 256 + k;
    p += e.x * hq[0] + e.y * hq[1] + e.z * hq[2] + e.w * hq[3];
  }
  sc[s][q] = p;
  __syncthreads();
  if (tid < 64) {
    float v = sc[tid][0] + sc[tid][1] + sc[tid][2] + sc[tid][3];
    bool m = (src_tok[tid * Bb + b] != PAD_TOK);
    red[tid] = m ? v : NEGV;
  }
  __syncthreads();
  if (tid < 64) {
    float v = red[tid];
    float mx = v;
    for (int o = 32; o; o >>= 1) mx = fmaxf(mx, __shfl_xor(mx, o));
    float e = __expf(v - mx);
    float sum = e;
    for (int o = 32; o; o >>= 1) sum += __shfl_xor(sum, o);
    attn[(long)tb * 64 + tid] = e / sum;
  }
}

// ---------------- context: ctx[tb][k] = sum_s attn[tb][s]*enc_out[s][b][k]
__global__ __launch_bounds__(256) void ctx_kernel(
    const float* __restrict__ attn, const float* __restrict__ enc_out,
    float* __restrict__ h1cat) {
  int tb = blockIdx.x;
  int b = tb & 31;
  __shared__ float as[64];
  int tid = threadIdx.x;
  if (tid < 64) as[tid] = attn[(long)tb * 64 + tid];
  __syncthreads();
  float4 acc = make_float4(0.f, 0.f, 0.f, 0.f);
  const float* eo = enc_out + (long)b * Hh + tid * 4;
  for (int s = 0; s < 64; s++) {
    float a = as[s];
    float4 e = *(const float4*)(eo + (long)s * Bb * Hh);
    acc.x += a * e.x; acc.y += a * e.y; acc.z += a * e.z; acc.w += a * e.w;
  }
  *(float4*)(h1cat + (long)tb * 2048 + 1024 + tid * 4) = acc;
}

extern "C" void kernel_launch(void* const* d_in, const int* in_sizes, int n_in,
                              void* d_out, int out_size, void* d_ws, size_t ws_size,
                              hipStream_t stream) {
  const int* src_tok = (const int*)d_in[0];
  const int* tgt_tok = (const int*)d_in[1];
  const float* enc_emb = (const float*)d_in[2];
  const float* eWih0 = (const float*)d_in[3];
  const float* eWhh0 = (const float*)d_in[4];
  const float* ebih0 = (const float*)d_in[5];
  const float* ebhh0 = (const float*)d_in[6];
  const float* eWih1 = (const float*)d_in[7];
  const float* eWhh1 = (const float*)d_in[8];
  const float* ebih1 = (const float*)d_in[9];
  const float* ebhh1 = (const float*)d_in[10];
  const float* dec_emb = (const float*)d_in[11];
  const float* dWih0 = (const float*)d_in[12];
  const float* dWhh0 = (const float*)d_in[13];
  const float* dbih0 = (const float*)d_in[14];
  const float* dbhh0 = (const float*)d_in[15];
  const float* dWih1 = (const float*)d_in[16];
  const float* dWhh1 = (const float*)d_in[17];
  const float* dbih1 = (const float*)d_in[18];
  const float* dbhh1 = (const float*)d_in[19];
  const float* Wc = (const float*)d_in[20];
  const float* bc = (const float*)d_in[21];
  const float* Wo = (const float*)d_in[22];
  const float* bo = (const float*)d_in[23];
  float* out = (float*)d_out;

  // workspace layout (floats); total ~38.4M floats (~154 MB) + barrier words
  float* w = (float*)d_ws;
  size_t o = 0;
  const size_t WT = (size_t)Hh * H3;  // 3,145,728
  float* eWhh0t = w + o; o += WT;
  float* eWih1t = w + o; o += WT;
  float* eWhh1t = w + o; o += WT;
  float* dWhh0t = w + o; o += WT;
  float* dWih1t = w + o; o += WT;
  float* dWhh1t = w + o; o += WT;
  float* gx0 = w + o;    o += (size_t)Ss * Bb * H3;       // reused enc then dec
  float* enc_out = w + o; o += (size_t)Ss * Bb * Hh;
  float* h1cat = w + o;  o += (size_t)DEC_T * Bb * 2 * Hh;
  float* h0buf = w + o;  o += (size_t)Bb * Hh;
  float* h1buf = w + o;  o += (size_t)Bb * Hh;            // adjacent to h0buf
  float* pgh0 = w + o;   o += (size_t)KS * Bb * H3;
  float* pgx1 = w + o;   o += (size_t)KS * Bb * H3;
  float* pgh1 = w + o;   o += (size_t)KS * Bb * H3;
  float* attnb = w + o;  o += (size_t)DEC_T * Bb * Ss;
  float* ccb = w + o;    o += (size_t)DEC_T * Bb * Hh;
  unsigned* bar = (unsigned*)(w + o); o += 128;           // 2x (cnt,flag) pairs

  // zero first output timestep, initial hidden state, barrier words
  hipMemsetAsync(out, 0, (size_t)Bb * Vv * sizeof(float), stream);
  hipMemsetAsync(h0buf, 0, (size_t)2 * Bb * Hh * sizeof(float), stream);
  hipMemsetAsync(bar, 0, 128 * sizeof(unsigned), stream);

  // one-time weight transposes [3072][1024] -> [1024][3072]
  dim3 tg(Hh / 32, H3 / 32);
  transpose_k<<<tg, 256, 0, stream>>>(eWhh0, eWhh0t, H3, Hh);
  transpose_k<<<tg, 256, 0, stream>>>(eWih1, eWih1t, H3, Hh);
  transpose_k<<<tg, 256, 0, stream>>>(eWhh1, eWhh1t, H3, Hh);
  transpose_k<<<tg, 256, 0, stream>>>(dWhh0, dWhh0t, H3, Hh);
  transpose_k<<<tg, 256, 0, stream>>>(dWih1, dWih1t, H3, Hh);
  transpose_k<<<tg, 256, 0, stream>>>(dWhh1, dWhh1t, H3, Hh);

  // encoder input gates for all timesteps: gx0 = emb[src] @ Wih0^T + bih0
  gemm_nt<0><<<dim3(H3 / 128, 16), 256, 0, stream>>>(
      enc_emb, src_tok, Ee, eWih0, Ee, ebih0, gx0, (long)H3, Ss * Bb, H3, Ee);

  // ---- encoder recurrence: one persistent launch (64 steps, 256 barriers)
  recurrence_pers<<<PGRID, 256, 0, stream>>>(
      gx0, eWhh0t, eWih1t, eWhh1t, ebhh0, ebih1, ebhh1,
      h0buf, h1buf, pgh0, pgx1, pgh1, enc_out, (long)Hh, Ss, bar);

  // decoder input gates for all 63 steps (reuses gx0; stream-ordered)
  gemm_nt<0><<<dim3(H3 / 128, 16), 256, 0, stream>>>(
      dec_emb, tgt_tok, Ee, dWih0, Ee, dbih0, gx0, (long)H3, DEC_T * Bb, H3, Ee);

  // ---- decoder recurrence: one persistent launch (63 steps, 252 barriers)
  recurrence_pers<<<PGRID, 256, 0, stream>>>(
      gx0, dWhh0t, dWih1t, dWhh1t, dbhh0, dbih1, dbhh1,
      h0buf, h1buf, pgh0, pgx1, pgh1, h1cat, (long)(2 * Hh), DEC_T, bar + 64);

  // ---- batched attention + context (deferred: doesn't feed the recurrence) ----
  attn_kernel<<<DEC_T * Bb, 256, 0, stream>>>(h1cat, enc_out, src_tok, attnb);
  ctx_kernel<<<DEC_T * Bb, 256, 0, stream>>>(attnb, enc_out, h1cat);

  // cc = tanh([h1, ctx] @ Wc^T + bc)
  gemm_nt<1><<<dim3(Hh / 128, 16), 256, 0, stream>>>(
      h1cat, nullptr, 2 * Hh, Wc, 2 * Hh, bc, ccb, (long)Hh, DEC_T * Bb, Hh, 2 * Hh);

  // logits = cc @ Wo^T + bo  -> rows [1..63] of output
  gemm_nt<0><<<dim3(Vv / 128, 16), 256, 0, stream>>>(
      ccb, nullptr, Hh, Wo, Hh, bo, out + (size_t)Bb * Vv, (long)Vv, DEC_T * Bb, Vv, Hh);
}